// Round 1
// baseline (788.539 us; speedup 1.0000x reference)
//
#include <hip/hip_runtime.h>
#include <hip/hip_bf16.h>

// Problem constants (match reference setup_inputs)
constexpr int N_NODES = 100000;
constexpr int N_EDGES = 20000;
constexpr int NNZ     = 800000;
constexpr int D       = 256;     // D_IN == D_OUT == 256

// ---------------- GEMM: H = X @ W + b  (fp32, register-tiled) ----------------
// BM=64 rows, BN=128 cols, BK=32. 256 threads, each computes 8x4 outputs.
constexpr int BM = 64, BN = 128, BK = 32;

__global__ __launch_bounds__(256) void gemm_xw_bias(
    const float* __restrict__ X, const float* __restrict__ W,
    const float* __restrict__ b, float* __restrict__ H, int M) {
  __shared__ float Xs[BM][BK + 1];   // +1 pad: conflict-free column reads
  __shared__ float Ws[BK][BN];       // natural layout, b128-friendly

  const int m0 = blockIdx.x * BM;
  const int n0 = blockIdx.y * BN;
  const int t  = threadIdx.x;
  const int tr = t >> 5;    // 0..7  -> rows tr*8 .. tr*8+7
  const int tc = t & 31;    // 0..31 -> cols tc*4 .. tc*4+3

  float acc[8][4] = {};

  for (int kt = 0; kt < D; kt += BK) {
    // Stage X tile: 64x32 floats = 512 float4, 2 per thread
#pragma unroll
    for (int q = 0; q < 2; ++q) {
      int idx = q * 256 + t;          // 0..511
      int r   = idx >> 3;             // 0..63
      int c4  = (idx & 7) << 2;       // 0,4,...,28
      int row = m0 + r;
      float4 v = make_float4(0.f, 0.f, 0.f, 0.f);
      if (row < M) v = *(const float4*)&X[row * D + kt + c4];
      Xs[r][c4 + 0] = v.x; Xs[r][c4 + 1] = v.y;
      Xs[r][c4 + 2] = v.z; Xs[r][c4 + 3] = v.w;
    }
    // Stage W tile: 32x128 floats = 1024 float4, 4 per thread
#pragma unroll
    for (int q = 0; q < 4; ++q) {
      int idx = q * 256 + t;          // 0..1023
      int r   = idx >> 5;             // 0..31
      int c4  = (idx & 31) << 2;      // 0..124
      *(float4*)&Ws[r][c4] = *(const float4*)&W[(kt + r) * D + n0 + c4];
    }
    __syncthreads();

#pragma unroll 8
    for (int k = 0; k < BK; ++k) {
      float4 wv = *(const float4*)&Ws[k][tc * 4];
      float xs[8];
#pragma unroll
      for (int i = 0; i < 8; ++i) xs[i] = Xs[tr * 8 + i][k];
#pragma unroll
      for (int i = 0; i < 8; ++i) {
        acc[i][0] += xs[i] * wv.x;
        acc[i][1] += xs[i] * wv.y;
        acc[i][2] += xs[i] * wv.z;
        acc[i][3] += xs[i] * wv.w;
      }
    }
    __syncthreads();
  }

  float4 bias = *(const float4*)&b[n0 + tc * 4];
#pragma unroll
  for (int i = 0; i < 8; ++i) {
    int row = m0 + tr * 8 + i;
    if (row < M) {
      float4 o;
      o.x = acc[i][0] + bias.x;
      o.y = acc[i][1] + bias.y;
      o.z = acc[i][2] + bias.z;
      o.w = acc[i][3] + bias.w;
      *(float4*)&H[row * D + n0 + tc * 4] = o;
    }
  }
}

// ---------------- CSR build: histogram -> scan -> scatter ----------------
__global__ void hist_kernel(const int* __restrict__ vidx,
                            const int* __restrict__ eidx,
                            int* __restrict__ node_cnt,
                            int* __restrict__ edge_cnt, int nnz) {
  int i = blockIdx.x * blockDim.x + threadIdx.x;
  if (i < nnz) {
    atomicAdd(&edge_cnt[eidx[i]], 1);
    atomicAdd(&node_cnt[vidx[i]], 1);
  }
}

// Two concurrent single-block exclusive scans (block 0: edges, block 1: nodes).
__global__ __launch_bounds__(1024) void dual_scan_kernel(
    const int* __restrict__ ecnt, int* __restrict__ eoff, int ne,
    const int* __restrict__ ncnt, int* __restrict__ noff, int nn) {
  const int* cnt; int* off; int n;
  if (blockIdx.x == 0) { cnt = ecnt; off = eoff; n = ne; }
  else                 { cnt = ncnt; off = noff; n = nn; }

  __shared__ int wsum[16];
  __shared__ int carry_s;
  const int tid  = threadIdx.x;
  const int lane = tid & 63;
  const int wid  = tid >> 6;
  if (tid == 0) carry_s = 0;
  __syncthreads();

  for (int base = 0; base < n; base += 1024) {
    int i = base + tid;
    int v = (i < n) ? cnt[i] : 0;
    // wave-inclusive scan (no syncs inside a wave)
    int x = v;
#pragma unroll
    for (int d = 1; d < 64; d <<= 1) {
      int y = __shfl_up(x, (unsigned)d, 64);
      if (lane >= d) x += y;
    }
    if (lane == 63) wsum[wid] = x;
    __syncthreads();
    if (wid == 0) {
      int s = (lane < 16) ? wsum[lane] : 0;
#pragma unroll
      for (int d = 1; d < 16; d <<= 1) {
        int y = __shfl_up(s, (unsigned)d, 64);
        if (lane >= d) s += y;
      }
      if (lane < 16) wsum[lane] = s;
    }
    __syncthreads();
    int wprev = (wid == 0) ? 0 : wsum[wid - 1];
    int incl  = carry_s + wprev + x;
    if (i < n) off[i] = incl - v;   // exclusive
    __syncthreads();
    if (tid == 1023) carry_s = incl;
    __syncthreads();
  }
  if (tid == 0) off[n] = carry_s;
}

__global__ void scatter_kernel(const int* __restrict__ vidx,
                               const int* __restrict__ eidx,
                               const int* __restrict__ eoff,
                               const int* __restrict__ noff,
                               int* __restrict__ ecur, int* __restrict__ ncur,
                               int* __restrict__ evals, int* __restrict__ nvals,
                               int nnz) {
  int i = blockIdx.x * blockDim.x + threadIdx.x;
  if (i < nnz) {
    int e = eidx[i], v = vidx[i];
    int p = atomicAdd(&ecur[e], 1);
    evals[eoff[e] + p] = v;     // vertices incident to edge e
    int q = atomicAdd(&ncur[v], 1);
    nvals[noff[v] + q] = e;     // edges incident to vertex v
  }
}

// ---------------- Segment means (gather, wave-per-segment) ----------------
// One wave per segment; lane handles 4 consecutive floats (float4), 64 lanes
// cover the full 256-wide row -> perfectly coalesced 1KB reads.
__global__ __launch_bounds__(256) void seg_mean_kernel(
    const float* __restrict__ src, const int* __restrict__ seg_off,
    const int* __restrict__ seg_vals, float* __restrict__ dst, int nseg) {
  int wid  = threadIdx.x >> 6;
  int lane = threadIdx.x & 63;
  int seg  = blockIdx.x * 4 + wid;
  if (seg >= nseg) return;
  int s = seg_off[seg], e = seg_off[seg + 1];
  float4 acc = make_float4(0.f, 0.f, 0.f, 0.f);
  for (int j = s; j < e; ++j) {
    int r = seg_vals[j];
    float4 v = *(const float4*)&src[r * D + lane * 4];
    acc.x += v.x; acc.y += v.y; acc.z += v.z; acc.w += v.w;
  }
  float inv = 1.0f / (float)max(e - s, 1);
  acc.x *= inv; acc.y *= inv; acc.z *= inv; acc.w *= inv;
  *(float4*)&dst[seg * D + lane * 4] = acc;
}

__global__ __launch_bounds__(256) void seg_mean_relu_kernel(
    const float* __restrict__ src, const int* __restrict__ seg_off,
    const int* __restrict__ seg_vals, float* __restrict__ dst, int nseg) {
  int wid  = threadIdx.x >> 6;
  int lane = threadIdx.x & 63;
  int seg  = blockIdx.x * 4 + wid;
  if (seg >= nseg) return;
  int s = seg_off[seg], e = seg_off[seg + 1];
  float4 acc = make_float4(0.f, 0.f, 0.f, 0.f);
  for (int j = s; j < e; ++j) {
    int r = seg_vals[j];
    float4 v = *(const float4*)&src[r * D + lane * 4];
    acc.x += v.x; acc.y += v.y; acc.z += v.z; acc.w += v.w;
  }
  float inv = 1.0f / (float)max(e - s, 1);
  float4 o;
  o.x = fmaxf(acc.x * inv, 0.f);
  o.y = fmaxf(acc.y * inv, 0.f);
  o.z = fmaxf(acc.z * inv, 0.f);
  o.w = fmaxf(acc.w * inv, 0.f);
  *(float4*)&dst[seg * D + lane * 4] = o;
}

// ---------------- Workspace layout (bytes) ----------------
// H:        100000*256*4 = 102,400,000
// Y:         20000*256*4 =  20,480,000
// zeroed int region: edge_cnt(20000) node_cnt(100000) edge_cur(20000) node_cur(100000)
// edge_off: 20001 ints; node_off: 100001 ints
// csr_edge_vals: 800000 ints; csr_node_vals: 800000 ints
constexpr size_t OFF_H        = 0;
constexpr size_t OFF_Y        = OFF_H + (size_t)N_NODES * D * 4;           // 102,400,000
constexpr size_t OFF_ZERO     = OFF_Y + (size_t)N_EDGES * D * 4;           // 122,880,000
constexpr size_t OFF_ECNT     = OFF_ZERO;
constexpr size_t OFF_NCNT     = OFF_ECNT + (size_t)N_EDGES * 4;
constexpr size_t OFF_ECUR     = OFF_NCNT + (size_t)N_NODES * 4;
constexpr size_t OFF_NCUR     = OFF_ECUR + (size_t)N_EDGES * 4;
constexpr size_t ZERO_BYTES   = (size_t)(N_EDGES + N_NODES) * 2 * 4;       // 960,000
constexpr size_t OFF_EOFF     = OFF_ZERO + ZERO_BYTES;
constexpr size_t OFF_NOFF     = OFF_EOFF + (size_t)(N_EDGES + 1) * 4;
constexpr size_t OFF_EVALS    = OFF_NOFF + (size_t)(N_NODES + 1) * 4;
constexpr size_t OFF_NVALS    = OFF_EVALS + (size_t)NNZ * 4;

extern "C" void kernel_launch(void* const* d_in, const int* in_sizes, int n_in,
                              void* d_out, int out_size, void* d_ws, size_t ws_size,
                              hipStream_t stream) {
  const float* X    = (const float*)d_in[0];
  const float* W    = (const float*)d_in[1];
  const float* b    = (const float*)d_in[2];
  const int*   vidx = (const int*)d_in[3];
  const int*   eidx = (const int*)d_in[4];
  float*       out  = (float*)d_out;

  char* ws = (char*)d_ws;
  float* H     = (float*)(ws + OFF_H);
  float* Y     = (float*)(ws + OFF_Y);
  int* ecnt    = (int*)(ws + OFF_ECNT);
  int* ncnt    = (int*)(ws + OFF_NCNT);
  int* ecur    = (int*)(ws + OFF_ECUR);
  int* ncur    = (int*)(ws + OFF_NCUR);
  int* eoff    = (int*)(ws + OFF_EOFF);
  int* noff    = (int*)(ws + OFF_NOFF);
  int* evals   = (int*)(ws + OFF_EVALS);
  int* nvals   = (int*)(ws + OFF_NVALS);

  // Zero the counter arrays (ws is re-poisoned to 0xAA before every launch)
  hipMemsetAsync(ws + OFF_ZERO, 0, ZERO_BYTES, stream);

  // H = X @ W + b
  dim3 ggrid((N_NODES + BM - 1) / BM, D / BN);
  gemm_xw_bias<<<ggrid, 256, 0, stream>>>(X, W, b, H, N_NODES);

  // CSR build (both directions in one pass)
  hist_kernel<<<(NNZ + 255) / 256, 256, 0, stream>>>(vidx, eidx, ncnt, ecnt, NNZ);
  dual_scan_kernel<<<2, 1024, 0, stream>>>(ecnt, eoff, N_EDGES, ncnt, noff, N_NODES);
  scatter_kernel<<<(NNZ + 255) / 256, 256, 0, stream>>>(vidx, eidx, eoff, noff,
                                                        ecur, ncur, evals, nvals, NNZ);

  // Y[e] = mean over incident vertices of H
  seg_mean_kernel<<<(N_EDGES + 3) / 4, 256, 0, stream>>>(H, eoff, evals, Y, N_EDGES);
  // out[v] = relu(mean over incident edges of Y)
  seg_mean_relu_kernel<<<(N_NODES + 3) / 4, 256, 0, stream>>>(Y, noff, nvals, out, N_NODES);
}

// Round 2
// 576.301 us; speedup vs baseline: 1.3683x; 1.3683x over previous
//
#include <hip/hip_runtime.h>
#include <hip/hip_bf16.h>

// Problem constants (match reference setup_inputs)
constexpr int N_NODES = 100000;
constexpr int N_EDGES = 20000;
constexpr int NNZ     = 800000;
constexpr int D       = 256;     // D_IN == D_OUT == 256

// ============ GEMM: Ye = Xe @ W + b  (fp32, register-tiled) ============
// Algebraic reorder: segment-mean is linear, so mean(X@W+b) == mean(X)@W+b.
// GEMM runs in EDGE space (M=20000), 5x smaller than node space.
constexpr int BM = 64, BN = 128, BK = 32;

__global__ __launch_bounds__(256) void gemm_xw_bias(
    const float* __restrict__ X, const float* __restrict__ W,
    const float* __restrict__ b, float* __restrict__ H, int M) {
  __shared__ float Xs[BM][BK + 1];
  __shared__ float Ws[BK][BN];

  const int m0 = blockIdx.x * BM;
  const int n0 = blockIdx.y * BN;
  const int t  = threadIdx.x;
  const int tr = t >> 5;
  const int tc = t & 31;

  float acc[8][4] = {};

  for (int kt = 0; kt < D; kt += BK) {
#pragma unroll
    for (int q = 0; q < 2; ++q) {
      int idx = q * 256 + t;
      int r   = idx >> 3;
      int c4  = (idx & 7) << 2;
      int row = m0 + r;
      float4 v = make_float4(0.f, 0.f, 0.f, 0.f);
      if (row < M) v = *(const float4*)&X[row * D + kt + c4];
      Xs[r][c4 + 0] = v.x; Xs[r][c4 + 1] = v.y;
      Xs[r][c4 + 2] = v.z; Xs[r][c4 + 3] = v.w;
    }
#pragma unroll
    for (int q = 0; q < 4; ++q) {
      int idx = q * 256 + t;
      int r   = idx >> 5;
      int c4  = (idx & 31) << 2;
      *(float4*)&Ws[r][c4] = *(const float4*)&W[(kt + r) * D + n0 + c4];
    }
    __syncthreads();

#pragma unroll 8
    for (int k = 0; k < BK; ++k) {
      float4 wv = *(const float4*)&Ws[k][tc * 4];
      float xs[8];
#pragma unroll
      for (int i = 0; i < 8; ++i) xs[i] = Xs[tr * 8 + i][k];
#pragma unroll
      for (int i = 0; i < 8; ++i) {
        acc[i][0] += xs[i] * wv.x;
        acc[i][1] += xs[i] * wv.y;
        acc[i][2] += xs[i] * wv.z;
        acc[i][3] += xs[i] * wv.w;
      }
    }
    __syncthreads();
  }

  float4 bias = *(const float4*)&b[n0 + tc * 4];
#pragma unroll
  for (int i = 0; i < 8; ++i) {
    int row = m0 + tr * 8 + i;
    if (row < M) {
      float4 o;
      o.x = acc[i][0] + bias.x;
      o.y = acc[i][1] + bias.y;
      o.z = acc[i][2] + bias.z;
      o.w = acc[i][3] + bias.w;
      *(float4*)&H[row * D + n0 + tc * 4] = o;
    }
  }
}

// ============ CSR build: histogram -> 3-phase scan -> scatter ============
__global__ void hist_kernel(const int* __restrict__ vidx,
                            const int* __restrict__ eidx,
                            int* __restrict__ node_cnt,
                            int* __restrict__ edge_cnt, int nnz) {
  int i = blockIdx.x * blockDim.x + threadIdx.x;
  if (i < nnz) {
    atomicAdd(&edge_cnt[eidx[i]], 1);
    atomicAdd(&node_cnt[vidx[i]], 1);
  }
}

// Combined scan over [ecnt (20000) || ncnt (100000)] = 120000 ints.
// Edge prefix sums total exactly NNZ, so node offsets = comb - NNZ.
constexpr int SCAN_L    = N_EDGES + N_NODES;     // 120000
constexpr int SCAN_TPB  = 1024;
constexpr int SCAN_EPT  = 4;
constexpr int SCAN_TILE = SCAN_TPB * SCAN_EPT;   // 4096
constexpr int SCAN_NB   = (SCAN_L + SCAN_TILE - 1) / SCAN_TILE;  // 30

__global__ __launch_bounds__(1024) void scan_phaseA(
    const int* __restrict__ cnt, int* __restrict__ comb, int* __restrict__ btot) {
  __shared__ int wsum[16];
  const int tid = threadIdx.x, lane = tid & 63, wid = tid >> 6;
  const int base = blockIdx.x * SCAN_TILE + tid * SCAN_EPT;
  int v[SCAN_EPT];
#pragma unroll
  for (int i = 0; i < SCAN_EPT; ++i) {
    int j = base + i;
    v[i] = (j < SCAN_L) ? cnt[j] : 0;
  }
  int tsum = v[0] + v[1] + v[2] + v[3];
  int x = tsum;
#pragma unroll
  for (int d = 1; d < 64; d <<= 1) {
    int y = __shfl_up(x, (unsigned)d, 64);
    if (lane >= d) x += y;
  }
  if (lane == 63) wsum[wid] = x;
  __syncthreads();
  if (wid == 0) {
    int s = (lane < 16) ? wsum[lane] : 0;
#pragma unroll
    for (int d = 1; d < 16; d <<= 1) {
      int y = __shfl_up(s, (unsigned)d, 64);
      if (lane >= d) s += y;
    }
    if (lane < 16) wsum[lane] = s;
  }
  __syncthreads();
  int texcl = ((wid == 0) ? 0 : wsum[wid - 1]) + (x - tsum);
  int run = texcl;
#pragma unroll
  for (int i = 0; i < SCAN_EPT; ++i) {
    int j = base + i;
    if (j < SCAN_L) comb[j] = run;
    run += v[i];
  }
  if (tid == 0) btot[blockIdx.x] = wsum[15];
}

__global__ void scan_phaseB(const int* __restrict__ btot, int* __restrict__ boff) {
  int lane = threadIdx.x;   // 64 threads, one wave
  int v = (lane < SCAN_NB) ? btot[lane] : 0;
  int x = v;
#pragma unroll
  for (int d = 1; d < 64; d <<= 1) {
    int y = __shfl_up(x, (unsigned)d, 64);
    if (lane >= d) x += y;
  }
  if (lane < SCAN_NB) boff[lane] = x - v;
}

__global__ __launch_bounds__(1024) void scan_phaseC(
    const int* __restrict__ comb, const int* __restrict__ boff,
    int* __restrict__ eoff, int* __restrict__ noff) {
  const int base = blockIdx.x * SCAN_TILE + threadIdx.x * SCAN_EPT;
  const int add = boff[blockIdx.x];
#pragma unroll
  for (int i = 0; i < SCAN_EPT; ++i) {
    int j = base + i;
    if (j < SCAN_L) {
      int val = comb[j] + add;
      if (j < N_EDGES) eoff[j] = val;
      else             noff[j - N_EDGES] = val - NNZ;
    }
  }
  if (blockIdx.x == 0 && threadIdx.x == 0) {
    eoff[N_EDGES] = NNZ;
    noff[N_NODES] = NNZ;
  }
}

__global__ void scatter_kernel(const int* __restrict__ vidx,
                               const int* __restrict__ eidx,
                               const int* __restrict__ eoff,
                               const int* __restrict__ noff,
                               int* __restrict__ ecur, int* __restrict__ ncur,
                               int* __restrict__ evals, int* __restrict__ nvals,
                               int nnz) {
  int i = blockIdx.x * blockDim.x + threadIdx.x;
  if (i < nnz) {
    int e = eidx[i], v = vidx[i];
    int p = atomicAdd(&ecur[e], 1);
    evals[eoff[e] + p] = v;
    int q = atomicAdd(&ncur[v], 1);
    nvals[noff[v] + q] = e;
  }
}

// ============ Segment means (gather, wave-per-segment) ============
__global__ __launch_bounds__(256) void seg_mean_kernel(
    const float* __restrict__ src, const int* __restrict__ seg_off,
    const int* __restrict__ seg_vals, float* __restrict__ dst, int nseg) {
  int wid  = threadIdx.x >> 6;
  int lane = threadIdx.x & 63;
  int seg  = blockIdx.x * 4 + wid;
  if (seg >= nseg) return;
  int s = seg_off[seg], e = seg_off[seg + 1];
  float4 acc = make_float4(0.f, 0.f, 0.f, 0.f);
  for (int j = s; j < e; ++j) {
    int r = seg_vals[j];
    float4 v = *(const float4*)&src[r * D + lane * 4];
    acc.x += v.x; acc.y += v.y; acc.z += v.z; acc.w += v.w;
  }
  float inv = 1.0f / (float)max(e - s, 1);
  acc.x *= inv; acc.y *= inv; acc.z *= inv; acc.w *= inv;
  *(float4*)&dst[seg * D + lane * 4] = acc;
}

__global__ __launch_bounds__(256) void seg_mean_relu_kernel(
    const float* __restrict__ src, const int* __restrict__ seg_off,
    const int* __restrict__ seg_vals, float* __restrict__ dst, int nseg) {
  int wid  = threadIdx.x >> 6;
  int lane = threadIdx.x & 63;
  int seg  = blockIdx.x * 4 + wid;
  if (seg >= nseg) return;
  int s = seg_off[seg], e = seg_off[seg + 1];
  float4 acc = make_float4(0.f, 0.f, 0.f, 0.f);
  for (int j = s; j < e; ++j) {
    int r = seg_vals[j];
    float4 v = *(const float4*)&src[r * D + lane * 4];
    acc.x += v.x; acc.y += v.y; acc.z += v.z; acc.w += v.w;
  }
  float inv = 1.0f / (float)max(e - s, 1);
  float4 o;
  o.x = fmaxf(acc.x * inv, 0.f);
  o.y = fmaxf(acc.y * inv, 0.f);
  o.z = fmaxf(acc.z * inv, 0.f);
  o.w = fmaxf(acc.w * inv, 0.f);
  *(float4*)&dst[seg * D + lane * 4] = o;
}

// ============ Workspace layout (bytes, 16B-aligned blocks) ============
constexpr size_t OFF_XE    = 0;                                        // 20000*256*4
constexpr size_t OFF_YE    = OFF_XE + (size_t)N_EDGES * D * 4;         // +20,480,000
constexpr size_t OFF_ZERO  = OFF_YE + (size_t)N_EDGES * D * 4;
constexpr size_t OFF_ECNT  = OFF_ZERO;                                 // 20000 ints
constexpr size_t OFF_NCNT  = OFF_ECNT + (size_t)N_EDGES * 4;           // 100000 ints (contiguous with ECNT!)
constexpr size_t OFF_ECUR  = OFF_NCNT + (size_t)N_NODES * 4;
constexpr size_t OFF_NCUR  = OFF_ECUR + (size_t)N_EDGES * 4;
constexpr size_t ZERO_BYTES = (size_t)(N_EDGES + N_NODES) * 2 * 4;     // 960,000
constexpr size_t OFF_EOFF  = OFF_ZERO + ZERO_BYTES;
constexpr size_t OFF_NOFF  = OFF_EOFF + (size_t)(N_EDGES + 1 + 3) * 4;
constexpr size_t OFF_EVALS = OFF_NOFF + (size_t)(N_NODES + 1 + 3) * 4;
constexpr size_t OFF_NVALS = OFF_EVALS + (size_t)NNZ * 4;
constexpr size_t OFF_COMB  = OFF_NVALS + (size_t)NNZ * 4;
constexpr size_t OFF_BTOT  = OFF_COMB + (size_t)SCAN_L * 4;
constexpr size_t OFF_BOFF  = OFF_BTOT + 128;

extern "C" void kernel_launch(void* const* d_in, const int* in_sizes, int n_in,
                              void* d_out, int out_size, void* d_ws, size_t ws_size,
                              hipStream_t stream) {
  const float* X    = (const float*)d_in[0];
  const float* W    = (const float*)d_in[1];
  const float* b    = (const float*)d_in[2];
  const int*   vidx = (const int*)d_in[3];
  const int*   eidx = (const int*)d_in[4];
  float*       out  = (float*)d_out;

  char* ws = (char*)d_ws;
  float* Xe   = (float*)(ws + OFF_XE);
  float* Ye   = (float*)(ws + OFF_YE);
  int* ecnt   = (int*)(ws + OFF_ECNT);
  int* ncnt   = (int*)(ws + OFF_NCNT);
  int* ecur   = (int*)(ws + OFF_ECUR);
  int* ncur   = (int*)(ws + OFF_NCUR);
  int* eoff   = (int*)(ws + OFF_EOFF);
  int* noff   = (int*)(ws + OFF_NOFF);
  int* evals  = (int*)(ws + OFF_EVALS);
  int* nvals  = (int*)(ws + OFF_NVALS);
  int* comb   = (int*)(ws + OFF_COMB);
  int* btot   = (int*)(ws + OFF_BTOT);
  int* boff   = (int*)(ws + OFF_BOFF);

  hipMemsetAsync(ws + OFF_ZERO, 0, ZERO_BYTES, stream);

  // CSR build (both directions)
  hist_kernel<<<(NNZ + 255) / 256, 256, 0, stream>>>(vidx, eidx, ncnt, ecnt, NNZ);
  scan_phaseA<<<SCAN_NB, SCAN_TPB, 0, stream>>>(ecnt, comb, btot);
  scan_phaseB<<<1, 64, 0, stream>>>(btot, boff);
  scan_phaseC<<<SCAN_NB, SCAN_TPB, 0, stream>>>(comb, boff, eoff, noff);
  scatter_kernel<<<(NNZ + 255) / 256, 256, 0, stream>>>(vidx, eidx, eoff, noff,
                                                        ecur, ncur, evals, nvals, NNZ);

  // Xe[e] = mean of incident vertex rows of X  (v2e in INPUT space)
  seg_mean_kernel<<<(N_EDGES + 3) / 4, 256, 0, stream>>>(X, eoff, evals, Xe, N_EDGES);

  // Ye = Xe @ W + b  (edge-space GEMM, 5x smaller than node-space)
  dim3 ggrid((N_EDGES + BM - 1) / BM, D / BN);
  gemm_xw_bias<<<ggrid, 256, 0, stream>>>(Xe, W, b, Ye, N_EDGES);

  // out[v] = relu(mean of incident edge rows of Ye)
  seg_mean_relu_kernel<<<(N_NODES + 3) / 4, 256, 0, stream>>>(Ye, noff, nvals, out, N_NODES);
}

// Round 3
// 490.987 us; speedup vs baseline: 1.6060x; 1.1738x over previous
//
#include <hip/hip_runtime.h>
#include <hip/hip_bf16.h>

// Problem constants (match reference setup_inputs)
constexpr int N_NODES = 100000;
constexpr int N_EDGES = 20000;
constexpr int NNZ     = 800000;
constexpr int D       = 256;     // D_IN == D_OUT == 256

typedef unsigned short ushort_t;
typedef unsigned short ushort4v __attribute__((ext_vector_type(4)));
typedef unsigned short ushort8v __attribute__((ext_vector_type(8)));
typedef __bf16         bf16x8   __attribute__((ext_vector_type(8)));
typedef float          f32x4    __attribute__((ext_vector_type(4)));

// fp32 -> bf16 bits, round-to-nearest-even (values are finite, no NaN path)
static __device__ inline ushort_t f2bf(float f) {
  unsigned u = __builtin_bit_cast(unsigned, f);
  return (ushort_t)((u + 0x7FFFu + ((u >> 16) & 1u)) >> 16);
}
static __device__ inline float bf2f(ushort_t h) {
  unsigned u = ((unsigned)h) << 16;
  return __builtin_bit_cast(float, u);
}

// ============ prep: cast X->bf16, transpose+cast W->Wt(bf16), histogram ============
constexpr int CAST_BLOCKS  = 6250;   // 25.6M floats / (256 thr * 4 float4)
constexpr int TRANS_BLOCKS = 64;     // 256x256 W, 4 rows/block
constexpr int HIST_BLOCKS  = 782;    // ceil(800000 / 1024)
constexpr int PREP_BLOCKS  = CAST_BLOCKS + TRANS_BLOCKS + HIST_BLOCKS;

__global__ __launch_bounds__(256) void prep_kernel(
    const float* __restrict__ X, const float* __restrict__ W,
    const int* __restrict__ vidx, const int* __restrict__ eidx,
    ushort_t* __restrict__ Xb, ushort_t* __restrict__ Wt,
    int* __restrict__ ncnt, int* __restrict__ ecnt) {
  const int blk = blockIdx.x, tid = threadIdx.x;
  if (blk < CAST_BLOCKS) {
    // X fp32 -> Xb bf16, coalesced float4 loads / ushort4 stores
#pragma unroll
    for (int q = 0; q < 4; ++q) {
      int idx4 = blk * 1024 + q * 256 + tid;       // float4 index
      float4 v = ((const float4*)X)[idx4];
      ushort4v o = { f2bf(v.x), f2bf(v.y), f2bf(v.z), f2bf(v.w) };
      *(ushort4v*)&Xb[(size_t)idx4 * 4] = o;
    }
  } else if (blk < CAST_BLOCKS + TRANS_BLOCKS) {
    // Wt[n][k] = bf16(W[k][n])  (transposed for MFMA B-fragment contiguity)
    int wb = blk - CAST_BLOCKS;
#pragma unroll
    for (int i = 0; i < 4; ++i) {
      int k = wb * 4 + i;
      Wt[(size_t)tid * 256 + k] = f2bf(W[(size_t)k * 256 + tid]);
    }
  } else {
    int hb = blk - CAST_BLOCKS - TRANS_BLOCKS;
#pragma unroll
    for (int q = 0; q < 4; ++q) {
      int i = hb * 1024 + q * 256 + tid;
      if (i < NNZ) {
        atomicAdd(&ecnt[eidx[i]], 1);
        atomicAdd(&ncnt[vidx[i]], 1);
      }
    }
  }
}

// ============ CSR build: 3-phase scan + scatter (unchanged from R2) ============
constexpr int SCAN_L    = N_EDGES + N_NODES;     // 120000
constexpr int SCAN_TPB  = 1024;
constexpr int SCAN_EPT  = 4;
constexpr int SCAN_TILE = SCAN_TPB * SCAN_EPT;   // 4096
constexpr int SCAN_NB   = (SCAN_L + SCAN_TILE - 1) / SCAN_TILE;  // 30

__global__ __launch_bounds__(1024) void scan_phaseA(
    const int* __restrict__ cnt, int* __restrict__ comb, int* __restrict__ btot) {
  __shared__ int wsum[16];
  const int tid = threadIdx.x, lane = tid & 63, wid = tid >> 6;
  const int base = blockIdx.x * SCAN_TILE + tid * SCAN_EPT;
  int v[SCAN_EPT];
#pragma unroll
  for (int i = 0; i < SCAN_EPT; ++i) {
    int j = base + i;
    v[i] = (j < SCAN_L) ? cnt[j] : 0;
  }
  int tsum = v[0] + v[1] + v[2] + v[3];
  int x = tsum;
#pragma unroll
  for (int d = 1; d < 64; d <<= 1) {
    int y = __shfl_up(x, (unsigned)d, 64);
    if (lane >= d) x += y;
  }
  if (lane == 63) wsum[wid] = x;
  __syncthreads();
  if (wid == 0) {
    int s = (lane < 16) ? wsum[lane] : 0;
#pragma unroll
    for (int d = 1; d < 16; d <<= 1) {
      int y = __shfl_up(s, (unsigned)d, 64);
      if (lane >= d) s += y;
    }
    if (lane < 16) wsum[lane] = s;
  }
  __syncthreads();
  int texcl = ((wid == 0) ? 0 : wsum[wid - 1]) + (x - tsum);
  int run = texcl;
#pragma unroll
  for (int i = 0; i < SCAN_EPT; ++i) {
    int j = base + i;
    if (j < SCAN_L) comb[j] = run;
    run += v[i];
  }
  if (tid == 0) btot[blockIdx.x] = wsum[15];
}

__global__ void scan_phaseB(const int* __restrict__ btot, int* __restrict__ boff) {
  int lane = threadIdx.x;
  int v = (lane < SCAN_NB) ? btot[lane] : 0;
  int x = v;
#pragma unroll
  for (int d = 1; d < 64; d <<= 1) {
    int y = __shfl_up(x, (unsigned)d, 64);
    if (lane >= d) x += y;
  }
  if (lane < SCAN_NB) boff[lane] = x - v;
}

__global__ __launch_bounds__(1024) void scan_phaseC(
    const int* __restrict__ comb, const int* __restrict__ boff,
    int* __restrict__ eoff, int* __restrict__ noff) {
  const int base = blockIdx.x * SCAN_TILE + threadIdx.x * SCAN_EPT;
  const int add = boff[blockIdx.x];
#pragma unroll
  for (int i = 0; i < SCAN_EPT; ++i) {
    int j = base + i;
    if (j < SCAN_L) {
      int val = comb[j] + add;
      if (j < N_EDGES) eoff[j] = val;
      else             noff[j - N_EDGES] = val - NNZ;
    }
  }
  if (blockIdx.x == 0 && threadIdx.x == 0) {
    eoff[N_EDGES] = NNZ;
    noff[N_NODES] = NNZ;
  }
}

__global__ void scatter_kernel(const int* __restrict__ vidx,
                               const int* __restrict__ eidx,
                               const int* __restrict__ eoff,
                               const int* __restrict__ noff,
                               int* __restrict__ ecur, int* __restrict__ ncur,
                               int* __restrict__ evals, int* __restrict__ nvals,
                               int nnz) {
  int i = blockIdx.x * blockDim.x + threadIdx.x;
  if (i < nnz) {
    int e = eidx[i], v = vidx[i];
    int p = atomicAdd(&ecur[e], 1);
    evals[eoff[e] + p] = v;
    int q = atomicAdd(&ncur[v], 1);
    nvals[noff[v] + q] = e;
  }
}

// ============ v2e: Xeb[e] = bf16(mean of bf16 X rows), fp32 accum ============
// Wave per segment; half-wave per row (32 lanes x 8 bf16 = 256 cols), 2 rows/iter.
__global__ __launch_bounds__(256) void v2e_mean(
    const ushort_t* __restrict__ Xb, const int* __restrict__ eoff,
    const int* __restrict__ evals, ushort_t* __restrict__ Xeb, int nseg) {
  int lane = threadIdx.x & 63;
  int half = lane >> 5, l32 = lane & 31;
  int seg  = blockIdx.x * 4 + (threadIdx.x >> 6);
  if (seg >= nseg) return;
  int s = eoff[seg], e = eoff[seg + 1];
  float a[8] = {};
  for (int j = s + half; j < e; j += 2) {
    int r = evals[j];
    ushort8v v = *(const ushort8v*)&Xb[(size_t)r * 256 + l32 * 8];
#pragma unroll
    for (int i = 0; i < 8; ++i) a[i] += bf2f(v[i]);
  }
#pragma unroll
  for (int i = 0; i < 8; ++i) a[i] += __shfl_down(a[i], 32);
  if (half == 0) {
    float inv = 1.0f / (float)max(e - s, 1);
    ushort8v o;
#pragma unroll
    for (int i = 0; i < 8; ++i) o[i] = f2bf(a[i] * inv);
    *(ushort8v*)&Xeb[(size_t)seg * 256 + l32 * 8] = o;
  }
}

// ============ GEMM (bf16 MFMA): Yeb = bf16(Xeb @ W + b) ============
// Grid = M/16 blocks (M=20000 -> 1250). Block = 4 waves; wave w covers cols
// [w*64, w*64+64). MFMA 16x16x32: A-frag A[m=lane&15][k=(lane>>4)*8+j],
// B-frag B[n=lane&15][k=(lane>>4)*8+j] from Wt[n][k]; D row=(lane>>4)*4+r,
// col=lane&15 (verified layouts, learn_hip m89/m120).
__global__ __launch_bounds__(256) void gemm_mfma(
    const ushort_t* __restrict__ A, const ushort_t* __restrict__ Wt,
    const float* __restrict__ bias, ushort_t* __restrict__ Ye) {
  const int w = threadIdx.x >> 6, lane = threadIdx.x & 63;
  const int m15 = lane & 15, q = lane >> 4;
  const int m0 = blockIdx.x * 16;
  const ushort_t* arow = A + (size_t)(m0 + m15) * 256 + q * 8;
  f32x4 acc[4] = { {0,0,0,0}, {0,0,0,0}, {0,0,0,0}, {0,0,0,0} };
  for (int k0 = 0; k0 < 256; k0 += 32) {
    bf16x8 af = __builtin_bit_cast(bf16x8, *(const ushort8v*)(arow + k0));
#pragma unroll
    for (int t = 0; t < 4; ++t) {
      const ushort_t* brow = Wt + (size_t)(w * 64 + t * 16 + m15) * 256 + k0 + q * 8;
      bf16x8 bf = __builtin_bit_cast(bf16x8, *(const ushort8v*)brow);
      acc[t] = __builtin_amdgcn_mfma_f32_16x16x32_bf16(af, bf, acc[t], 0, 0, 0);
    }
  }
#pragma unroll
  for (int t = 0; t < 4; ++t) {
    int col = w * 64 + t * 16 + m15;
    float bv = bias[col];
#pragma unroll
    for (int r = 0; r < 4; ++r) {
      int row = m0 + q * 4 + r;
      Ye[(size_t)row * 256 + col] = f2bf(acc[t][r] + bv);
    }
  }
}

// ============ e2v: out[v] = relu(mean of bf16 Ye rows), fp32 out ============
__global__ __launch_bounds__(256) void e2v_mean_relu(
    const ushort_t* __restrict__ Yeb, const int* __restrict__ noff,
    const int* __restrict__ nvals, float* __restrict__ dst, int nseg) {
  int lane = threadIdx.x & 63;
  int half = lane >> 5, l32 = lane & 31;
  int seg  = blockIdx.x * 4 + (threadIdx.x >> 6);
  if (seg >= nseg) return;
  int s = noff[seg], e = noff[seg + 1];
  float a[8] = {};
  for (int j = s + half; j < e; j += 2) {
    int r = nvals[j];
    ushort8v v = *(const ushort8v*)&Yeb[(size_t)r * 256 + l32 * 8];
#pragma unroll
    for (int i = 0; i < 8; ++i) a[i] += bf2f(v[i]);
  }
#pragma unroll
  for (int i = 0; i < 8; ++i) a[i] += __shfl_down(a[i], 32);
  if (half == 0) {
    float inv = 1.0f / (float)max(e - s, 1);
    float4 o0, o1;
    o0.x = fmaxf(a[0] * inv, 0.f); o0.y = fmaxf(a[1] * inv, 0.f);
    o0.z = fmaxf(a[2] * inv, 0.f); o0.w = fmaxf(a[3] * inv, 0.f);
    o1.x = fmaxf(a[4] * inv, 0.f); o1.y = fmaxf(a[5] * inv, 0.f);
    o1.z = fmaxf(a[6] * inv, 0.f); o1.w = fmaxf(a[7] * inv, 0.f);
    size_t base = (size_t)seg * 256 + l32 * 8;
    *(float4*)&dst[base]     = o0;
    *(float4*)&dst[base + 4] = o1;
  }
}

// ============ Workspace layout (bytes) ============
constexpr size_t OFF_XB    = 0;                                         // 51,200,000
constexpr size_t OFF_XEB   = OFF_XB  + (size_t)N_NODES * D * 2;
constexpr size_t OFF_YEB   = OFF_XEB + (size_t)N_EDGES * D * 2;
constexpr size_t OFF_WT    = OFF_YEB + (size_t)N_EDGES * D * 2;
constexpr size_t OFF_ZERO  = OFF_WT  + (size_t)D * D * 2;
constexpr size_t OFF_ECNT  = OFF_ZERO;
constexpr size_t OFF_NCNT  = OFF_ECNT + (size_t)N_EDGES * 4;            // contiguous with ECNT
constexpr size_t OFF_ECUR  = OFF_NCNT + (size_t)N_NODES * 4;
constexpr size_t OFF_NCUR  = OFF_ECUR + (size_t)N_EDGES * 4;
constexpr size_t ZERO_BYTES = (size_t)(N_EDGES + N_NODES) * 2 * 4;      // 960,000
constexpr size_t OFF_EOFF  = OFF_ZERO + ZERO_BYTES;
constexpr size_t OFF_NOFF  = OFF_EOFF + (size_t)(N_EDGES + 1 + 3) * 4;
constexpr size_t OFF_EVALS = OFF_NOFF + (size_t)(N_NODES + 1 + 3) * 4;
constexpr size_t OFF_NVALS = OFF_EVALS + (size_t)NNZ * 4;
constexpr size_t OFF_COMB  = OFF_NVALS + (size_t)NNZ * 4;
constexpr size_t OFF_BTOT  = OFF_COMB + (size_t)SCAN_L * 4;
constexpr size_t OFF_BOFF  = OFF_BTOT + 128;

extern "C" void kernel_launch(void* const* d_in, const int* in_sizes, int n_in,
                              void* d_out, int out_size, void* d_ws, size_t ws_size,
                              hipStream_t stream) {
  const float* X    = (const float*)d_in[0];
  const float* W    = (const float*)d_in[1];
  const float* b    = (const float*)d_in[2];
  const int*   vidx = (const int*)d_in[3];
  const int*   eidx = (const int*)d_in[4];
  float*       out  = (float*)d_out;

  char* ws = (char*)d_ws;
  ushort_t* Xb   = (ushort_t*)(ws + OFF_XB);
  ushort_t* Xeb  = (ushort_t*)(ws + OFF_XEB);
  ushort_t* Yeb  = (ushort_t*)(ws + OFF_YEB);
  ushort_t* Wt   = (ushort_t*)(ws + OFF_WT);
  int* ecnt  = (int*)(ws + OFF_ECNT);
  int* ncnt  = (int*)(ws + OFF_NCNT);
  int* ecur  = (int*)(ws + OFF_ECUR);
  int* ncur  = (int*)(ws + OFF_NCUR);
  int* eoff  = (int*)(ws + OFF_EOFF);
  int* noff  = (int*)(ws + OFF_NOFF);
  int* evals = (int*)(ws + OFF_EVALS);
  int* nvals = (int*)(ws + OFF_NVALS);
  int* comb  = (int*)(ws + OFF_COMB);
  int* btot  = (int*)(ws + OFF_BTOT);
  int* boff  = (int*)(ws + OFF_BOFF);

  hipMemsetAsync(ws + OFF_ZERO, 0, ZERO_BYTES, stream);

  // fused: cast X->bf16, transpose W->Wt bf16, histogram
  prep_kernel<<<PREP_BLOCKS, 256, 0, stream>>>(X, W, vidx, eidx, Xb, Wt, ncnt, ecnt);

  scan_phaseA<<<SCAN_NB, SCAN_TPB, 0, stream>>>(ecnt, comb, btot);
  scan_phaseB<<<1, 64, 0, stream>>>(btot, boff);
  scan_phaseC<<<SCAN_NB, SCAN_TPB, 0, stream>>>(comb, boff, eoff, noff);
  scatter_kernel<<<(NNZ + 255) / 256, 256, 0, stream>>>(vidx, eidx, eoff, noff,
                                                        ecur, ncur, evals, nvals, NNZ);

  // Xeb[e] = bf16(mean of incident X rows)
  v2e_mean<<<(N_EDGES + 3) / 4, 256, 0, stream>>>(Xb, eoff, evals, Xeb, N_EDGES);

  // Yeb = bf16(Xeb @ W + b) via MFMA
  gemm_mfma<<<N_EDGES / 16, 256, 0, stream>>>(Xeb, Wt, b, Yeb);

  // out[v] = relu(mean of incident Ye rows)
  e2v_mean_relu<<<(N_NODES + 3) / 4, 256, 0, stream>>>(Yeb, noff, nvals, out, N_NODES);
}

// Round 4
// 440.058 us; speedup vs baseline: 1.7919x; 1.1157x over previous
//
#include <hip/hip_runtime.h>
#include <hip/hip_bf16.h>

// Problem constants (match reference setup_inputs)
constexpr int N_NODES = 100000;
constexpr int N_EDGES = 20000;
constexpr int NNZ     = 800000;
constexpr int D       = 256;     // D_IN == D_OUT == 256

typedef unsigned short ushort_t;
typedef unsigned short ushort4v __attribute__((ext_vector_type(4)));
typedef unsigned short ushort8v __attribute__((ext_vector_type(8)));
typedef __bf16         bf16x8   __attribute__((ext_vector_type(8)));
typedef float          f32x4    __attribute__((ext_vector_type(4)));

// fp32 -> bf16 bits, round-to-nearest-even (finite values only)
static __device__ inline ushort_t f2bf(float f) {
  unsigned u = __builtin_bit_cast(unsigned, f);
  return (ushort_t)((u + 0x7FFFu + ((u >> 16) & 1u)) >> 16);
}
static __device__ inline float bf2f(ushort_t h) {
  unsigned u = ((unsigned)h) << 16;
  return __builtin_bit_cast(float, u);
}

// ============ prep: cast X->bf16 | transpose W | rank-recording histogram ============
// Rank trick: the atomicAdd RETURN VALUE is the entry's within-segment slot,
// so the later scatter needs no atomics at all (halves total device atomics).
constexpr int CAST_BLOCKS  = 6250;   // 6.4M float4 / (256 thr * 4)
constexpr int TRANS_BLOCKS = 64;     // 256x256 W, 4 rows/block
constexpr int HIST_BLOCKS  = 782;    // ceil(200000 int4 / 256)
constexpr int PREP_BLOCKS  = CAST_BLOCKS + TRANS_BLOCKS + HIST_BLOCKS;

__global__ __launch_bounds__(256) void prep_kernel(
    const float* __restrict__ X, const float* __restrict__ W,
    const int* __restrict__ vidx, const int* __restrict__ eidx,
    ushort_t* __restrict__ Xb, ushort_t* __restrict__ Wt,
    int* __restrict__ ncnt, int* __restrict__ ecnt,
    int* __restrict__ erank, int* __restrict__ nrank) {
  const int blk = blockIdx.x, tid = threadIdx.x;
  if (blk < CAST_BLOCKS) {
#pragma unroll
    for (int q = 0; q < 4; ++q) {
      int idx4 = blk * 1024 + q * 256 + tid;
      float4 v = ((const float4*)X)[idx4];
      ushort4v o = { f2bf(v.x), f2bf(v.y), f2bf(v.z), f2bf(v.w) };
      *(ushort4v*)&Xb[(size_t)idx4 * 4] = o;
    }
  } else if (blk < CAST_BLOCKS + TRANS_BLOCKS) {
    int wb = blk - CAST_BLOCKS;
#pragma unroll
    for (int i = 0; i < 4; ++i) {
      int k = wb * 4 + i;
      Wt[(size_t)tid * 256 + k] = f2bf(W[(size_t)k * 256 + tid]);
    }
  } else {
    int i4 = (blk - CAST_BLOCKS - TRANS_BLOCKS) * 256 + tid;
    if (i4 < NNZ / 4) {
      int4 e4 = ((const int4*)eidx)[i4];
      int4 v4 = ((const int4*)vidx)[i4];
      int4 er, nr;
      er.x = atomicAdd(&ecnt[e4.x], 1);  nr.x = atomicAdd(&ncnt[v4.x], 1);
      er.y = atomicAdd(&ecnt[e4.y], 1);  nr.y = atomicAdd(&ncnt[v4.y], 1);
      er.z = atomicAdd(&ecnt[e4.z], 1);  nr.z = atomicAdd(&ncnt[v4.z], 1);
      er.w = atomicAdd(&ecnt[e4.w], 1);  nr.w = atomicAdd(&ncnt[v4.w], 1);
      ((int4*)erank)[i4] = er;
      ((int4*)nrank)[i4] = nr;
    }
  }
}

// ============ 3-phase scan over [ecnt || ncnt] (120000 ints) ============
constexpr int SCAN_L    = N_EDGES + N_NODES;
constexpr int SCAN_TPB  = 1024;
constexpr int SCAN_EPT  = 4;
constexpr int SCAN_TILE = SCAN_TPB * SCAN_EPT;
constexpr int SCAN_NB   = (SCAN_L + SCAN_TILE - 1) / SCAN_TILE;  // 30

__global__ __launch_bounds__(1024) void scan_phaseA(
    const int* __restrict__ cnt, int* __restrict__ comb, int* __restrict__ btot) {
  __shared__ int wsum[16];
  const int tid = threadIdx.x, lane = tid & 63, wid = tid >> 6;
  const int base = blockIdx.x * SCAN_TILE + tid * SCAN_EPT;
  int v[SCAN_EPT];
#pragma unroll
  for (int i = 0; i < SCAN_EPT; ++i) {
    int j = base + i;
    v[i] = (j < SCAN_L) ? cnt[j] : 0;
  }
  int tsum = v[0] + v[1] + v[2] + v[3];
  int x = tsum;
#pragma unroll
  for (int d = 1; d < 64; d <<= 1) {
    int y = __shfl_up(x, (unsigned)d, 64);
    if (lane >= d) x += y;
  }
  if (lane == 63) wsum[wid] = x;
  __syncthreads();
  if (wid == 0) {
    int s = (lane < 16) ? wsum[lane] : 0;
#pragma unroll
    for (int d = 1; d < 16; d <<= 1) {
      int y = __shfl_up(s, (unsigned)d, 64);
      if (lane >= d) s += y;
    }
    if (lane < 16) wsum[lane] = s;
  }
  __syncthreads();
  int texcl = ((wid == 0) ? 0 : wsum[wid - 1]) + (x - tsum);
  int run = texcl;
#pragma unroll
  for (int i = 0; i < SCAN_EPT; ++i) {
    int j = base + i;
    if (j < SCAN_L) comb[j] = run;
    run += v[i];
  }
  if (tid == 0) btot[blockIdx.x] = wsum[15];
}

__global__ void scan_phaseB(const int* __restrict__ btot, int* __restrict__ boff) {
  int lane = threadIdx.x;
  int v = (lane < SCAN_NB) ? btot[lane] : 0;
  int x = v;
#pragma unroll
  for (int d = 1; d < 64; d <<= 1) {
    int y = __shfl_up(x, (unsigned)d, 64);
    if (lane >= d) x += y;
  }
  if (lane < SCAN_NB) boff[lane] = x - v;
}

__global__ __launch_bounds__(1024) void scan_phaseC(
    const int* __restrict__ comb, const int* __restrict__ boff,
    int* __restrict__ eoff, int* __restrict__ noff) {
  const int base = blockIdx.x * SCAN_TILE + threadIdx.x * SCAN_EPT;
  const int add = boff[blockIdx.x];
#pragma unroll
  for (int i = 0; i < SCAN_EPT; ++i) {
    int j = base + i;
    if (j < SCAN_L) {
      int val = comb[j] + add;
      if (j < N_EDGES) eoff[j] = val;
      else             noff[j - N_EDGES] = val - NNZ;
    }
  }
  if (blockIdx.x == 0 && threadIdx.x == 0) {
    eoff[N_EDGES] = NNZ;
    noff[N_NODES] = NNZ;
  }
}

// ============ scatter: NO atomics (uses recorded ranks) ============
__global__ __launch_bounds__(256) void scatter_norank(
    const int* __restrict__ vidx, const int* __restrict__ eidx,
    const int* __restrict__ eoff, const int* __restrict__ noff,
    const int* __restrict__ erank, const int* __restrict__ nrank,
    int* __restrict__ evals, int* __restrict__ nvals) {
  int i4 = blockIdx.x * 256 + threadIdx.x;
  if (i4 < NNZ / 4) {
    int4 e4 = ((const int4*)eidx)[i4];
    int4 v4 = ((const int4*)vidx)[i4];
    int4 er = ((const int4*)erank)[i4];
    int4 nr = ((const int4*)nrank)[i4];
    evals[eoff[e4.x] + er.x] = v4.x;  nvals[noff[v4.x] + nr.x] = e4.x;
    evals[eoff[e4.y] + er.y] = v4.y;  nvals[noff[v4.y] + nr.y] = e4.y;
    evals[eoff[e4.z] + er.z] = v4.z;  nvals[noff[v4.z] + nr.z] = e4.z;
    evals[eoff[e4.w] + er.w] = v4.w;  nvals[noff[v4.w] + nr.w] = e4.w;
  }
}

// ============ v2e: Xeb[e] = bf16(mean of bf16 X rows), fp32 accum ============
__global__ __launch_bounds__(256) void v2e_mean(
    const ushort_t* __restrict__ Xb, const int* __restrict__ eoff,
    const int* __restrict__ evals, ushort_t* __restrict__ Xeb, int nseg) {
  int lane = threadIdx.x & 63;
  int half = lane >> 5, l32 = lane & 31;
  int seg  = blockIdx.x * 4 + (threadIdx.x >> 6);
  if (seg >= nseg) return;
  int s = eoff[seg], e = eoff[seg + 1];
  float a[8] = {};
  for (int j = s + half; j < e; j += 2) {
    int r = evals[j];
    ushort8v v = *(const ushort8v*)&Xb[(size_t)r * 256 + l32 * 8];
#pragma unroll
    for (int i = 0; i < 8; ++i) a[i] += bf2f(v[i]);
  }
#pragma unroll
  for (int i = 0; i < 8; ++i) a[i] += __shfl_down(a[i], 32);
  if (half == 0) {
    float inv = 1.0f / (float)max(e - s, 1);
    ushort8v o;
#pragma unroll
    for (int i = 0; i < 8; ++i) o[i] = f2bf(a[i] * inv);
    *(ushort8v*)&Xeb[(size_t)seg * 256 + l32 * 8] = o;
  }
}

// ============ GEMM (bf16 MFMA): Yeb = bf16(Xeb @ W + b) ============
__global__ __launch_bounds__(256) void gemm_mfma(
    const ushort_t* __restrict__ A, const ushort_t* __restrict__ Wt,
    const float* __restrict__ bias, ushort_t* __restrict__ Ye) {
  const int w = threadIdx.x >> 6, lane = threadIdx.x & 63;
  const int m15 = lane & 15, q = lane >> 4;
  const int m0 = blockIdx.x * 16;
  const ushort_t* arow = A + (size_t)(m0 + m15) * 256 + q * 8;
  f32x4 acc[4] = { {0,0,0,0}, {0,0,0,0}, {0,0,0,0}, {0,0,0,0} };
  for (int k0 = 0; k0 < 256; k0 += 32) {
    bf16x8 af = __builtin_bit_cast(bf16x8, *(const ushort8v*)(arow + k0));
#pragma unroll
    for (int t = 0; t < 4; ++t) {
      const ushort_t* brow = Wt + (size_t)(w * 64 + t * 16 + m15) * 256 + k0 + q * 8;
      bf16x8 bf = __builtin_bit_cast(bf16x8, *(const ushort8v*)brow);
      acc[t] = __builtin_amdgcn_mfma_f32_16x16x32_bf16(af, bf, acc[t], 0, 0, 0);
    }
  }
#pragma unroll
  for (int t = 0; t < 4; ++t) {
    int col = w * 64 + t * 16 + m15;
    float bv = bias[col];
#pragma unroll
    for (int r = 0; r < 4; ++r) {
      int row = m0 + q * 4 + r;
      Ye[(size_t)row * 256 + col] = f2bf(acc[t][r] + bv);
    }
  }
}

// ============ e2v: out[v] = relu(mean of bf16 Ye rows), fp32 out ============
__global__ __launch_bounds__(256) void e2v_mean_relu(
    const ushort_t* __restrict__ Yeb, const int* __restrict__ noff,
    const int* __restrict__ nvals, float* __restrict__ dst, int nseg) {
  int lane = threadIdx.x & 63;
  int half = lane >> 5, l32 = lane & 31;
  int seg  = blockIdx.x * 4 + (threadIdx.x >> 6);
  if (seg >= nseg) return;
  int s = noff[seg], e = noff[seg + 1];
  float a[8] = {};
  for (int j = s + half; j < e; j += 2) {
    int r = nvals[j];
    ushort8v v = *(const ushort8v*)&Yeb[(size_t)r * 256 + l32 * 8];
#pragma unroll
    for (int i = 0; i < 8; ++i) a[i] += bf2f(v[i]);
  }
#pragma unroll
  for (int i = 0; i < 8; ++i) a[i] += __shfl_down(a[i], 32);
  if (half == 0) {
    float inv = 1.0f / (float)max(e - s, 1);
    float4 o0, o1;
    o0.x = fmaxf(a[0] * inv, 0.f); o0.y = fmaxf(a[1] * inv, 0.f);
    o0.z = fmaxf(a[2] * inv, 0.f); o0.w = fmaxf(a[3] * inv, 0.f);
    o1.x = fmaxf(a[4] * inv, 0.f); o1.y = fmaxf(a[5] * inv, 0.f);
    o1.z = fmaxf(a[6] * inv, 0.f); o1.w = fmaxf(a[7] * inv, 0.f);
    size_t base = (size_t)seg * 256 + l32 * 8;
    *(float4*)&dst[base]     = o0;
    *(float4*)&dst[base + 4] = o1;
  }
}

// ============ Workspace layout (bytes; every block 16B-aligned) ============
constexpr size_t OFF_XB    = 0;                                    // 51,200,000
constexpr size_t OFF_XEB   = OFF_XB  + (size_t)N_NODES * D * 2;
constexpr size_t OFF_YEB   = OFF_XEB + (size_t)N_EDGES * D * 2;
constexpr size_t OFF_WT    = OFF_YEB + (size_t)N_EDGES * D * 2;
constexpr size_t OFF_ZERO  = OFF_WT  + (size_t)D * D * 2;
constexpr size_t OFF_ECNT  = OFF_ZERO;                             // 20000 ints
constexpr size_t OFF_NCNT  = OFF_ECNT + (size_t)N_EDGES * 4;       // contiguous!
constexpr size_t ZERO_BYTES = (size_t)(N_EDGES + N_NODES) * 4;     // 480,000
constexpr size_t OFF_EOFF  = OFF_ZERO + ZERO_BYTES;
constexpr size_t OFF_NOFF  = OFF_EOFF + (size_t)(N_EDGES + 1 + 3) * 4;
constexpr size_t OFF_EVALS = OFF_NOFF + (size_t)(N_NODES + 1 + 3) * 4;
constexpr size_t OFF_NVALS = OFF_EVALS + (size_t)NNZ * 4;
constexpr size_t OFF_ERANK = OFF_NVALS + (size_t)NNZ * 4;
constexpr size_t OFF_NRANK = OFF_ERANK + (size_t)NNZ * 4;
constexpr size_t OFF_COMB  = OFF_NRANK + (size_t)NNZ * 4;
constexpr size_t OFF_BTOT  = OFF_COMB + (size_t)SCAN_L * 4;
constexpr size_t OFF_BOFF  = OFF_BTOT + 128;

extern "C" void kernel_launch(void* const* d_in, const int* in_sizes, int n_in,
                              void* d_out, int out_size, void* d_ws, size_t ws_size,
                              hipStream_t stream) {
  const float* X    = (const float*)d_in[0];
  const float* W    = (const float*)d_in[1];
  const float* b    = (const float*)d_in[2];
  const int*   vidx = (const int*)d_in[3];
  const int*   eidx = (const int*)d_in[4];
  float*       out  = (float*)d_out;

  char* ws = (char*)d_ws;
  ushort_t* Xb   = (ushort_t*)(ws + OFF_XB);
  ushort_t* Xeb  = (ushort_t*)(ws + OFF_XEB);
  ushort_t* Yeb  = (ushort_t*)(ws + OFF_YEB);
  ushort_t* Wt   = (ushort_t*)(ws + OFF_WT);
  int* ecnt  = (int*)(ws + OFF_ECNT);
  int* ncnt  = (int*)(ws + OFF_NCNT);
  int* eoff  = (int*)(ws + OFF_EOFF);
  int* noff  = (int*)(ws + OFF_NOFF);
  int* evals = (int*)(ws + OFF_EVALS);
  int* nvals = (int*)(ws + OFF_NVALS);
  int* erank = (int*)(ws + OFF_ERANK);
  int* nrank = (int*)(ws + OFF_NRANK);
  int* comb  = (int*)(ws + OFF_COMB);
  int* btot  = (int*)(ws + OFF_BTOT);
  int* boff  = (int*)(ws + OFF_BOFF);

  hipMemsetAsync(ws + OFF_ZERO, 0, ZERO_BYTES, stream);

  // cast X->bf16 | transpose W | rank-recording histogram (1 atomic/entry/dir)
  prep_kernel<<<PREP_BLOCKS, 256, 0, stream>>>(X, W, vidx, eidx, Xb, Wt,
                                               ncnt, ecnt, erank, nrank);

  scan_phaseA<<<SCAN_NB, SCAN_TPB, 0, stream>>>(ecnt, comb, btot);
  scan_phaseB<<<1, 64, 0, stream>>>(btot, boff);
  scan_phaseC<<<SCAN_NB, SCAN_TPB, 0, stream>>>(comb, boff, eoff, noff);

  // atomic-free scatter using recorded ranks
  scatter_norank<<<(NNZ / 4 + 255) / 256, 256, 0, stream>>>(
      vidx, eidx, eoff, noff, erank, nrank, evals, nvals);

  // Xeb[e] = bf16(mean of incident X rows)
  v2e_mean<<<(N_EDGES + 3) / 4, 256, 0, stream>>>(Xb, eoff, evals, Xeb, N_EDGES);

  // Yeb = bf16(Xeb @ W + b) via MFMA
  gemm_mfma<<<N_EDGES / 16, 256, 0, stream>>>(Xeb, Wt, b, Yeb);

  // out[v] = relu(mean of incident Ye rows)
  e2v_mean_relu<<<(N_NODES + 3) / 4, 256, 0, stream>>>(Yeb, noff, nvals, out, N_NODES);
}

// Round 5
// 419.947 us; speedup vs baseline: 1.8777x; 1.0479x over previous
//
#include <hip/hip_runtime.h>
#include <hip/hip_bf16.h>

// Problem constants (match reference setup_inputs)
constexpr int N_NODES = 100000;
constexpr int N_EDGES = 20000;
constexpr int NNZ     = 800000;
constexpr int D       = 256;     // D_IN == D_OUT == 256

typedef unsigned short ushort_t;
typedef unsigned short ushort4v __attribute__((ext_vector_type(4)));
typedef unsigned short ushort8v __attribute__((ext_vector_type(8)));
typedef __bf16         bf16x8   __attribute__((ext_vector_type(8)));
typedef float          f32x4    __attribute__((ext_vector_type(4)));
typedef float          f32x8    __attribute__((ext_vector_type(8)));

// fp32 -> bf16 bits, round-to-nearest-even (finite values only)
static __device__ inline ushort_t f2bf(float f) {
  unsigned u = __builtin_bit_cast(unsigned, f);
  return (ushort_t)((u + 0x7FFFu + ((u >> 16) & 1u)) >> 16);
}

// 8 bf16 -> 8 f32 (backend may select packed cvt / v_pk_add_f32 downstream)
static __device__ inline f32x8 row_f32(const ushort_t* p) {
  bf16x8 b = __builtin_bit_cast(bf16x8, *(const ushort8v*)p);
  return __builtin_convertvector(b, f32x8);
}

// ============ prep: HIST FIRST (latency hides under cast BW) ============
// Rank trick: atomicAdd return value = within-segment slot, so the scatter
// needs no atomics. Hist blocks are dispatched first so all 1.6M device
// atomics are in flight while cast blocks stream X.
constexpr int HIST_BLOCKS  = 782;    // ceil(200000 int4 / 256)
constexpr int TRANS_BLOCKS = 64;     // 256x256 W, 4 rows/block
constexpr int CAST_BLOCKS  = 6250;   // 6.4M float4 / (256 thr * 4)
constexpr int PREP_BLOCKS  = HIST_BLOCKS + TRANS_BLOCKS + CAST_BLOCKS;

__global__ __launch_bounds__(256) void prep_kernel(
    const float* __restrict__ X, const float* __restrict__ W,
    const int* __restrict__ vidx, const int* __restrict__ eidx,
    ushort_t* __restrict__ Xb, ushort_t* __restrict__ Wt,
    int* __restrict__ ncnt, int* __restrict__ ecnt,
    int* __restrict__ erank, int* __restrict__ nrank) {
  const int blk = blockIdx.x, tid = threadIdx.x;
  if (blk < HIST_BLOCKS) {
    int i4 = blk * 256 + tid;
    if (i4 < NNZ / 4) {
      int4 e4 = ((const int4*)eidx)[i4];
      int4 v4 = ((const int4*)vidx)[i4];
      int4 er, nr;
      er.x = atomicAdd(&ecnt[e4.x], 1);  nr.x = atomicAdd(&ncnt[v4.x], 1);
      er.y = atomicAdd(&ecnt[e4.y], 1);  nr.y = atomicAdd(&ncnt[v4.y], 1);
      er.z = atomicAdd(&ecnt[e4.z], 1);  nr.z = atomicAdd(&ncnt[v4.z], 1);
      er.w = atomicAdd(&ecnt[e4.w], 1);  nr.w = atomicAdd(&ncnt[v4.w], 1);
      ((int4*)erank)[i4] = er;
      ((int4*)nrank)[i4] = nr;
    }
  } else if (blk < HIST_BLOCKS + TRANS_BLOCKS) {
    int wb = blk - HIST_BLOCKS;
#pragma unroll
    for (int i = 0; i < 4; ++i) {
      int k = wb * 4 + i;
      Wt[(size_t)tid * 256 + k] = f2bf(W[(size_t)k * 256 + tid]);
    }
  } else {
    int cb = blk - HIST_BLOCKS - TRANS_BLOCKS;
#pragma unroll
    for (int q = 0; q < 4; ++q) {
      int idx4 = cb * 1024 + q * 256 + tid;
      float4 v = ((const float4*)X)[idx4];
      ushort4v o = { f2bf(v.x), f2bf(v.y), f2bf(v.z), f2bf(v.w) };
      *(ushort4v*)&Xb[(size_t)idx4 * 4] = o;
    }
  }
}

// ============ 3-phase scan over [ecnt || ncnt] (120000 ints) ============
constexpr int SCAN_L    = N_EDGES + N_NODES;
constexpr int SCAN_TPB  = 1024;
constexpr int SCAN_EPT  = 4;
constexpr int SCAN_TILE = SCAN_TPB * SCAN_EPT;
constexpr int SCAN_NB   = (SCAN_L + SCAN_TILE - 1) / SCAN_TILE;  // 30

__global__ __launch_bounds__(1024) void scan_phaseA(
    const int* __restrict__ cnt, int* __restrict__ comb, int* __restrict__ btot) {
  __shared__ int wsum[16];
  const int tid = threadIdx.x, lane = tid & 63, wid = tid >> 6;
  const int base = blockIdx.x * SCAN_TILE + tid * SCAN_EPT;
  int v[SCAN_EPT];
#pragma unroll
  for (int i = 0; i < SCAN_EPT; ++i) {
    int j = base + i;
    v[i] = (j < SCAN_L) ? cnt[j] : 0;
  }
  int tsum = v[0] + v[1] + v[2] + v[3];
  int x = tsum;
#pragma unroll
  for (int d = 1; d < 64; d <<= 1) {
    int y = __shfl_up(x, (unsigned)d, 64);
    if (lane >= d) x += y;
  }
  if (lane == 63) wsum[wid] = x;
  __syncthreads();
  if (wid == 0) {
    int s = (lane < 16) ? wsum[lane] : 0;
#pragma unroll
    for (int d = 1; d < 16; d <<= 1) {
      int y = __shfl_up(s, (unsigned)d, 64);
      if (lane >= d) s += y;
    }
    if (lane < 16) wsum[lane] = s;
  }
  __syncthreads();
  int texcl = ((wid == 0) ? 0 : wsum[wid - 1]) + (x - tsum);
  int run = texcl;
#pragma unroll
  for (int i = 0; i < SCAN_EPT; ++i) {
    int j = base + i;
    if (j < SCAN_L) comb[j] = run;
    run += v[i];
  }
  if (tid == 0) btot[blockIdx.x] = wsum[15];
}

__global__ void scan_phaseB(const int* __restrict__ btot, int* __restrict__ boff) {
  int lane = threadIdx.x;
  int v = (lane < SCAN_NB) ? btot[lane] : 0;
  int x = v;
#pragma unroll
  for (int d = 1; d < 64; d <<= 1) {
    int y = __shfl_up(x, (unsigned)d, 64);
    if (lane >= d) x += y;
  }
  if (lane < SCAN_NB) boff[lane] = x - v;
}

__global__ __launch_bounds__(1024) void scan_phaseC(
    const int* __restrict__ comb, const int* __restrict__ boff,
    int* __restrict__ eoff, int* __restrict__ noff) {
  const int base = blockIdx.x * SCAN_TILE + threadIdx.x * SCAN_EPT;
  const int add = boff[blockIdx.x];
#pragma unroll
  for (int i = 0; i < SCAN_EPT; ++i) {
    int j = base + i;
    if (j < SCAN_L) {
      int val = comb[j] + add;
      if (j < N_EDGES) eoff[j] = val;
      else             noff[j - N_EDGES] = val - NNZ;
    }
  }
  if (blockIdx.x == 0 && threadIdx.x == 0) {
    eoff[N_EDGES] = NNZ;
    noff[N_NODES] = NNZ;
  }
}

// ============ scatter: NO atomics (uses recorded ranks) ============
__global__ __launch_bounds__(256) void scatter_norank(
    const int* __restrict__ vidx, const int* __restrict__ eidx,
    const int* __restrict__ eoff, const int* __restrict__ noff,
    const int* __restrict__ erank, const int* __restrict__ nrank,
    int* __restrict__ evals, int* __restrict__ nvals) {
  int i4 = blockIdx.x * 256 + threadIdx.x;
  if (i4 < NNZ / 4) {
    int4 e4 = ((const int4*)eidx)[i4];
    int4 v4 = ((const int4*)vidx)[i4];
    int4 er = ((const int4*)erank)[i4];
    int4 nr = ((const int4*)nrank)[i4];
    evals[eoff[e4.x] + er.x] = v4.x;  nvals[noff[v4.x] + nr.x] = e4.x;
    evals[eoff[e4.y] + er.y] = v4.y;  nvals[noff[v4.y] + nr.y] = e4.y;
    evals[eoff[e4.z] + er.z] = v4.z;  nvals[noff[v4.z] + nr.z] = e4.z;
    evals[eoff[e4.w] + er.w] = v4.w;  nvals[noff[v4.w] + nr.w] = e4.w;
  }
}

// ============ v2e: Xeb[e] = bf16(mean of bf16 X rows) ============
// Half-wave per row (32 lanes x 8 bf16 = 256 cols); 4-row unroll keeps 4
// independent index loads + 4 independent 16B row loads in flight (MLP).
__global__ __launch_bounds__(256) void v2e_mean(
    const ushort_t* __restrict__ Xb, const int* __restrict__ eoff,
    const int* __restrict__ evals, ushort_t* __restrict__ Xeb, int nseg) {
  int lane = threadIdx.x & 63;
  int half = lane >> 5, l32 = lane & 31;
  int seg  = blockIdx.x * 4 + (threadIdx.x >> 6);
  if (seg >= nseg) return;
  int s = eoff[seg], e = eoff[seg + 1];
  f32x8 acc = {0, 0, 0, 0, 0, 0, 0, 0};
  int j = s + half;
  for (; j + 6 < e; j += 8) {
    int r0 = evals[j], r1 = evals[j + 2], r2 = evals[j + 4], r3 = evals[j + 6];
    f32x8 f0 = row_f32(&Xb[(size_t)r0 * 256 + l32 * 8]);
    f32x8 f1 = row_f32(&Xb[(size_t)r1 * 256 + l32 * 8]);
    f32x8 f2 = row_f32(&Xb[(size_t)r2 * 256 + l32 * 8]);
    f32x8 f3 = row_f32(&Xb[(size_t)r3 * 256 + l32 * 8]);
    acc += (f0 + f1) + (f2 + f3);
  }
  for (; j < e; j += 2)
    acc += row_f32(&Xb[(size_t)evals[j] * 256 + l32 * 8]);
  float r[8];
#pragma unroll
  for (int i = 0; i < 8; ++i) r[i] = acc[i] + __shfl_down(acc[i], 32);
  if (half == 0) {
    float inv = 1.0f / (float)max(e - s, 1);
    ushort8v o;
#pragma unroll
    for (int i = 0; i < 8; ++i) o[i] = f2bf(r[i] * inv);
    *(ushort8v*)&Xeb[(size_t)seg * 256 + l32 * 8] = o;
  }
}

// ============ GEMM (bf16 MFMA): Yeb = bf16(Xeb @ W + b) ============
__global__ __launch_bounds__(256) void gemm_mfma(
    const ushort_t* __restrict__ A, const ushort_t* __restrict__ Wt,
    const float* __restrict__ bias, ushort_t* __restrict__ Ye) {
  const int w = threadIdx.x >> 6, lane = threadIdx.x & 63;
  const int m15 = lane & 15, q = lane >> 4;
  const int m0 = blockIdx.x * 16;
  const ushort_t* arow = A + (size_t)(m0 + m15) * 256 + q * 8;
  f32x4 acc[4] = { {0,0,0,0}, {0,0,0,0}, {0,0,0,0}, {0,0,0,0} };
  for (int k0 = 0; k0 < 256; k0 += 32) {
    bf16x8 af = __builtin_bit_cast(bf16x8, *(const ushort8v*)(arow + k0));
#pragma unroll
    for (int t = 0; t < 4; ++t) {
      const ushort_t* brow = Wt + (size_t)(w * 64 + t * 16 + m15) * 256 + k0 + q * 8;
      bf16x8 bf = __builtin_bit_cast(bf16x8, *(const ushort8v*)brow);
      acc[t] = __builtin_amdgcn_mfma_f32_16x16x32_bf16(af, bf, acc[t], 0, 0, 0);
    }
  }
#pragma unroll
  for (int t = 0; t < 4; ++t) {
    int col = w * 64 + t * 16 + m15;
    float bv = bias[col];
#pragma unroll
    for (int r = 0; r < 4; ++r) {
      int row = m0 + q * 4 + r;
      Ye[(size_t)row * 256 + col] = f2bf(acc[t][r] + bv);
    }
  }
}

// ============ e2v: out[v] = relu(mean of bf16 Ye rows), fp32 out ============
// deg mean = 8 -> the 4-row unrolled body is exactly one iteration per half.
__global__ __launch_bounds__(256) void e2v_mean_relu(
    const ushort_t* __restrict__ Yeb, const int* __restrict__ noff,
    const int* __restrict__ nvals, float* __restrict__ dst, int nseg) {
  int lane = threadIdx.x & 63;
  int half = lane >> 5, l32 = lane & 31;
  int seg  = blockIdx.x * 4 + (threadIdx.x >> 6);
  if (seg >= nseg) return;
  int s = noff[seg], e = noff[seg + 1];
  f32x8 acc = {0, 0, 0, 0, 0, 0, 0, 0};
  int j = s + half;
  for (; j + 6 < e; j += 8) {
    int r0 = nvals[j], r1 = nvals[j + 2], r2 = nvals[j + 4], r3 = nvals[j + 6];
    f32x8 f0 = row_f32(&Yeb[(size_t)r0 * 256 + l32 * 8]);
    f32x8 f1 = row_f32(&Yeb[(size_t)r1 * 256 + l32 * 8]);
    f32x8 f2 = row_f32(&Yeb[(size_t)r2 * 256 + l32 * 8]);
    f32x8 f3 = row_f32(&Yeb[(size_t)r3 * 256 + l32 * 8]);
    acc += (f0 + f1) + (f2 + f3);
  }
  for (; j < e; j += 2)
    acc += row_f32(&Yeb[(size_t)nvals[j] * 256 + l32 * 8]);
  float r[8];
#pragma unroll
  for (int i = 0; i < 8; ++i) r[i] = acc[i] + __shfl_down(acc[i], 32);
  if (half == 0) {
    float inv = 1.0f / (float)max(e - s, 1);
    float4 o0, o1;
    o0.x = fmaxf(r[0] * inv, 0.f); o0.y = fmaxf(r[1] * inv, 0.f);
    o0.z = fmaxf(r[2] * inv, 0.f); o0.w = fmaxf(r[3] * inv, 0.f);
    o1.x = fmaxf(r[4] * inv, 0.f); o1.y = fmaxf(r[5] * inv, 0.f);
    o1.z = fmaxf(r[6] * inv, 0.f); o1.w = fmaxf(r[7] * inv, 0.f);
    size_t base = (size_t)seg * 256 + l32 * 8;
    *(float4*)&dst[base]     = o0;
    *(float4*)&dst[base + 4] = o1;
  }
}

// ============ Workspace layout (bytes; every block 16B-aligned) ============
constexpr size_t OFF_XB    = 0;                                    // 51,200,000
constexpr size_t OFF_XEB   = OFF_XB  + (size_t)N_NODES * D * 2;
constexpr size_t OFF_YEB   = OFF_XEB + (size_t)N_EDGES * D * 2;
constexpr size_t OFF_WT    = OFF_YEB + (size_t)N_EDGES * D * 2;
constexpr size_t OFF_ZERO  = OFF_WT  + (size_t)D * D * 2;
constexpr size_t OFF_ECNT  = OFF_ZERO;                             // 20000 ints
constexpr size_t OFF_NCNT  = OFF_ECNT + (size_t)N_EDGES * 4;       // contiguous!
constexpr size_t ZERO_BYTES = (size_t)(N_EDGES + N_NODES) * 4;     // 480,000
constexpr size_t OFF_EOFF  = OFF_ZERO + ZERO_BYTES;
constexpr size_t OFF_NOFF  = OFF_EOFF + (size_t)(N_EDGES + 1 + 3) * 4;
constexpr size_t OFF_EVALS = OFF_NOFF + (size_t)(N_NODES + 1 + 3) * 4;
constexpr size_t OFF_NVALS = OFF_EVALS + (size_t)NNZ * 4;
constexpr size_t OFF_ERANK = OFF_NVALS + (size_t)NNZ * 4;
constexpr size_t OFF_NRANK = OFF_ERANK + (size_t)NNZ * 4;
constexpr size_t OFF_COMB  = OFF_NRANK + (size_t)NNZ * 4;
constexpr size_t OFF_BTOT  = OFF_COMB + (size_t)SCAN_L * 4;
constexpr size_t OFF_BOFF  = OFF_BTOT + 128;

extern "C" void kernel_launch(void* const* d_in, const int* in_sizes, int n_in,
                              void* d_out, int out_size, void* d_ws, size_t ws_size,
                              hipStream_t stream) {
  const float* X    = (const float*)d_in[0];
  const float* W    = (const float*)d_in[1];
  const float* b    = (const float*)d_in[2];
  const int*   vidx = (const int*)d_in[3];
  const int*   eidx = (const int*)d_in[4];
  float*       out  = (float*)d_out;

  char* ws = (char*)d_ws;
  ushort_t* Xb   = (ushort_t*)(ws + OFF_XB);
  ushort_t* Xeb  = (ushort_t*)(ws + OFF_XEB);
  ushort_t* Yeb  = (ushort_t*)(ws + OFF_YEB);
  ushort_t* Wt   = (ushort_t*)(ws + OFF_WT);
  int* ecnt  = (int*)(ws + OFF_ECNT);
  int* ncnt  = (int*)(ws + OFF_NCNT);
  int* eoff  = (int*)(ws + OFF_EOFF);
  int* noff  = (int*)(ws + OFF_NOFF);
  int* evals = (int*)(ws + OFF_EVALS);
  int* nvals = (int*)(ws + OFF_NVALS);
  int* erank = (int*)(ws + OFF_ERANK);
  int* nrank = (int*)(ws + OFF_NRANK);
  int* comb  = (int*)(ws + OFF_COMB);
  int* btot  = (int*)(ws + OFF_BTOT);
  int* boff  = (int*)(ws + OFF_BOFF);

  hipMemsetAsync(ws + OFF_ZERO, 0, ZERO_BYTES, stream);

  // hist (first -> atomics overlap cast) | transpose W | cast X->bf16
  prep_kernel<<<PREP_BLOCKS, 256, 0, stream>>>(X, W, vidx, eidx, Xb, Wt,
                                               ncnt, ecnt, erank, nrank);

  scan_phaseA<<<SCAN_NB, SCAN_TPB, 0, stream>>>(ecnt, comb, btot);
  scan_phaseB<<<1, 64, 0, stream>>>(btot, boff);
  scan_phaseC<<<SCAN_NB, SCAN_TPB, 0, stream>>>(comb, boff, eoff, noff);

  // atomic-free scatter using recorded ranks
  scatter_norank<<<(NNZ / 4 + 255) / 256, 256, 0, stream>>>(
      vidx, eidx, eoff, noff, erank, nrank, evals, nvals);

  // Xeb[e] = bf16(mean of incident X rows)
  v2e_mean<<<(N_EDGES + 3) / 4, 256, 0, stream>>>(Xb, eoff, evals, Xeb, N_EDGES);

  // Yeb = bf16(Xeb @ W + b) via MFMA
  gemm_mfma<<<N_EDGES / 16, 256, 0, stream>>>(Xeb, Wt, b, Yeb);

  // out[v] = relu(mean of incident Ye rows)
  e2v_mean_relu<<<(N_NODES + 3) / 4, 256, 0, stream>>>(Yeb, noff, nvals, out, N_NODES);
}